// Round 1
// baseline (211.766 us; speedup 1.0000x reference)
//
#include <hip/hip_runtime.h>
#include <hip/hip_bf16.h>
#include <stdint.h>

#define SEQ 4096
#define DIN 1024
#define DOUT 1024

typedef __bf16 bf16;
typedef __bf16 bf16x4v __attribute__((ext_vector_type(4)));
typedef __bf16 bf16x8v __attribute__((ext_vector_type(8)));
typedef float f32x4 __attribute__((ext_vector_type(4)));

#define AS1 __attribute__((address_space(1)))
#define AS3 __attribute__((address_space(3)))

__device__ __forceinline__ void load_lds16(const void* g, void* l) {
  __builtin_amdgcn_global_load_lds((const AS1 uint32_t*)g, (AS3 uint32_t*)l, 16, 0, 0);
}

// ---------------- cast fp32 -> bf16, 4 elems/thread ----------------
__global__ __launch_bounds__(256) void cast_kernel(const float* __restrict__ in,
                                                   bf16* __restrict__ out, int n) {
  int i = (blockIdx.x * 256 + threadIdx.x) * 4;
  if (i >= n) return;
  float4 v = *reinterpret_cast<const float4*>(in + i);
  bf16x4v o;
  o[0] = (bf16)v.x; o[1] = (bf16)v.y; o[2] = (bf16)v.z; o[3] = (bf16)v.w;
  *reinterpret_cast<bf16x4v*>(out + i) = o;
}

// ---------------- BT GEMM core: C[128x128] += A[brow..][k] * B[bcol..][k]^T ----
// A: [M x lda] bf16 row-major, B: [N x ldb] bf16 row-major (K contiguous both).
// 256 threads = 4 waves (2x2), each wave 64x64 out = 4x4 frags of 16x16x32 MFMA.
__device__ __forceinline__ void gemm_bt_core(const bf16* __restrict__ A,
                                             const bf16* __restrict__ B,
                                             int lda, int ldb, int brow, int bcol,
                                             int kend, f32x4 acc[4][4],
                                             bf16* At, bf16* Bt) {
  const int tid = threadIdx.x;
  const int lane = tid & 63;
  const int wr = (tid >> 7) & 1;
  const int wc = (tid >> 6) & 1;

  // staging: linear LDS offsets, 2 issues per operand (256 thr * 16B = 4KB each)
  const int off0 = tid * 16;        // [0, 4096)
  const int off1 = off0 + 4096;     // [4096, 8192)
  const int r0 = off0 >> 6, c0 = off0 & 63;   // tile row / byte-in-row (64B rows)
  const int r1 = off1 >> 6, c1 = off1 & 63;
  const char* A0 = (const char*)A + (size_t)(brow + r0) * (size_t)(lda * 2) + c0;
  const char* A1 = (const char*)A + (size_t)(brow + r1) * (size_t)(lda * 2) + c1;
  const char* B0 = (const char*)B + (size_t)(bcol + r0) * (size_t)(ldb * 2) + c0;
  const char* B1 = (const char*)B + (size_t)(bcol + r1) * (size_t)(ldb * 2) + c1;

  const int lrow = lane & 15;
  const int lk = (lane >> 4) * 16;  // byte offset of this lane's k-group

  for (int k0 = 0; k0 < kend; k0 += 32) {
    const size_t kb = (size_t)k0 * 2;
    load_lds16(A0 + kb, (char*)At + off0);
    load_lds16(A1 + kb, (char*)At + off1);
    load_lds16(B0 + kb, (char*)Bt + off0);
    load_lds16(B1 + kb, (char*)Bt + off1);
    __syncthreads();   // includes vmcnt(0) drain

    bf16x8v a[4], b[4];
#pragma unroll
    for (int mt = 0; mt < 4; ++mt)
      a[mt] = *(const bf16x8v*)((const char*)At + ((wr * 64 + mt * 16 + lrow) * 64 + lk));
#pragma unroll
    for (int nt = 0; nt < 4; ++nt)
      b[nt] = *(const bf16x8v*)((const char*)Bt + ((wc * 64 + nt * 16 + lrow) * 64 + lk));
#pragma unroll
    for (int mt = 0; mt < 4; ++mt)
#pragma unroll
      for (int nt = 0; nt < 4; ++nt)
        acc[mt][nt] = __builtin_amdgcn_mfma_f32_16x16x32_bf16(a[mt], b[nt], acc[mt][nt], 0, 0, 0);
    __syncthreads();
  }
}

#define ACC_INIT()                    \
  f32x4 acc[4][4];                    \
  {                                   \
    f32x4 z = {0.f, 0.f, 0.f, 0.f};  \
    for (int m = 0; m < 4; ++m)       \
      for (int n = 0; n < 4; ++n) acc[m][n] = z; \
  }

// ---------------- QKV projection: Q,K row-major bf16; V written transposed ----
__global__ __launch_bounds__(256) void qkv_kernel(const bf16* __restrict__ xb,
                                                  const bf16* __restrict__ Wq,
                                                  const bf16* __restrict__ Wk,
                                                  const bf16* __restrict__ Wv,
                                                  bf16* __restrict__ Q,
                                                  bf16* __restrict__ K,
                                                  bf16* __restrict__ Vt) {
  __shared__ bf16 At[128 * 32];
  __shared__ bf16 Bt[128 * 32];
  const int bj = blockIdx.x, bi = blockIdx.y, z = blockIdx.z;
  const bf16* W = (z == 0) ? Wq : (z == 1) ? Wk : Wv;
  ACC_INIT();
  gemm_bt_core(xb, W, DIN, DIN, bi * 128, bj * 128, DIN, acc, At, Bt);
  const int lane = threadIdx.x & 63;
  const int wr = (threadIdx.x >> 7) & 1, wc = (threadIdx.x >> 6) & 1;
  const int rbase = bi * 128 + wr * 64 + ((lane >> 4) << 2);
  const int cbase = bj * 128 + wc * 64 + (lane & 15);
  if (z < 2) {
    bf16* O = (z == 0) ? Q : K;
#pragma unroll
    for (int mt = 0; mt < 4; ++mt)
#pragma unroll
      for (int nt = 0; nt < 4; ++nt)
#pragma unroll
        for (int j = 0; j < 4; ++j)
          O[(size_t)(rbase + mt * 16 + j) * DOUT + (cbase + nt * 16)] = (bf16)acc[mt][nt][j];
  } else {
#pragma unroll
    for (int mt = 0; mt < 4; ++mt)
#pragma unroll
      for (int nt = 0; nt < 4; ++nt)
#pragma unroll
        for (int j = 0; j < 4; ++j)
          Vt[(size_t)(cbase + nt * 16) * SEQ + (rbase + mt * 16 + j)] = (bf16)acc[mt][nt][j];
  }
}

// ---------------- scores = Q @ K^T * scale, lower-triangle blocks only --------
__global__ __launch_bounds__(256) void scores_kernel(const bf16* __restrict__ Q,
                                                     const bf16* __restrict__ Km,
                                                     float* __restrict__ Sc) {
  const int bj = blockIdx.x, bi = blockIdx.y;
  if (bj > bi) return;
  __shared__ bf16 At[128 * 32];
  __shared__ bf16 Bt[128 * 32];
  ACC_INIT();
  gemm_bt_core(Q, Km, DOUT, DOUT, bi * 128, bj * 128, DOUT, acc, At, Bt);
  const int lane = threadIdx.x & 63;
  const int wr = (threadIdx.x >> 7) & 1, wc = (threadIdx.x >> 6) & 1;
  const int rbase = bi * 128 + wr * 64 + ((lane >> 4) << 2);
  const int cbase = bj * 128 + wc * 64 + (lane & 15);
  const float scale = 0.03125f;  // 1/sqrt(1024)
#pragma unroll
  for (int mt = 0; mt < 4; ++mt)
#pragma unroll
    for (int nt = 0; nt < 4; ++nt)
#pragma unroll
      for (int j = 0; j < 4; ++j)
        Sc[(size_t)(rbase + mt * 16 + j) * SEQ + (cbase + nt * 16)] = acc[mt][nt][j] * scale;
}

// ---------------- row softmax: P[r][0..r]=softmax, zero-fill to 128 boundary --
__global__ __launch_bounds__(256) void softmax_kernel(const float* __restrict__ Sc,
                                                      bf16* __restrict__ P) {
  __shared__ float rowbuf[SEQ];
  __shared__ float red[8];
  const int r = blockIdx.x;
  const int n = r + 1;
  const int nw = ((r >> 7) + 1) << 7;
  const int tid = threadIdx.x;
  const float* src = Sc + (size_t)r * SEQ;

  float lmax = -__builtin_inff();
  for (int c = tid; c < n; c += 256) {
    float v = src[c];
    rowbuf[c] = v;
    lmax = fmaxf(lmax, v);
  }
#pragma unroll
  for (int m = 32; m >= 1; m >>= 1) lmax = fmaxf(lmax, __shfl_xor(lmax, m, 64));
  if ((tid & 63) == 0) red[tid >> 6] = lmax;
  __syncthreads();
  const float rmax = fmaxf(fmaxf(red[0], red[1]), fmaxf(red[2], red[3]));

  float lsum = 0.f;
  for (int c = tid; c < n; c += 256) {
    float e = __expf(rowbuf[c] - rmax);
    rowbuf[c] = e;
    lsum += e;
  }
#pragma unroll
  for (int m = 32; m >= 1; m >>= 1) lsum += __shfl_xor(lsum, m, 64);
  if ((tid & 63) == 0) red[4 + (tid >> 6)] = lsum;
  __syncthreads();
  const float inv = 1.0f / (red[4] + red[5] + red[6] + red[7]);

  bf16* dst = P + (size_t)r * SEQ;
  for (int c = tid; c < n; c += 256) dst[c] = (bf16)(rowbuf[c] * inv);
  for (int c = n + tid - (n & ~255); c < nw; c += 256) {  // cover [n, nw)
    if (c >= n) dst[c] = (bf16)0.f;
  }
}

// ---------------- out = P @ V  (= P @ Vt^T), causal K-cap ---------------------
__global__ __launch_bounds__(256) void pv_kernel(const bf16* __restrict__ P,
                                                 const bf16* __restrict__ Vt,
                                                 float* __restrict__ Out) {
  __shared__ bf16 At[128 * 32];
  __shared__ bf16 Bt[128 * 32];
  const int bj = blockIdx.x, bi = blockIdx.y;
  ACC_INIT();
  gemm_bt_core(P, Vt, SEQ, SEQ, bi * 128, bj * 128, (bi + 1) * 128, acc, At, Bt);
  const int lane = threadIdx.x & 63;
  const int wr = (threadIdx.x >> 7) & 1, wc = (threadIdx.x >> 6) & 1;
  const int rbase = bi * 128 + wr * 64 + ((lane >> 4) << 2);
  const int cbase = bj * 128 + wc * 64 + (lane & 15);
#pragma unroll
  for (int mt = 0; mt < 4; ++mt)
#pragma unroll
    for (int nt = 0; nt < 4; ++nt)
#pragma unroll
      for (int j = 0; j < 4; ++j)
        Out[(size_t)(rbase + mt * 16 + j) * DOUT + (cbase + nt * 16)] = acc[mt][nt][j];
}

extern "C" void kernel_launch(void* const* d_in, const int* in_sizes, int n_in,
                              void* d_out, int out_size, void* d_ws, size_t ws_size,
                              hipStream_t stream) {
  const float* x  = (const float*)d_in[0];
  const float* Wq = (const float*)d_in[1];
  const float* Wk = (const float*)d_in[2];
  const float* Wv = (const float*)d_in[3];
  float* Out = (float*)d_out;

  char* base = (char*)d_ws;
  bf16* xb  = (bf16*)(base + 0);          //  8 MB  [4096x1024]
  bf16* wqb = (bf16*)(base + 8388608);    //  2 MB
  bf16* wkb = (bf16*)(base + 10485760);   //  2 MB
  bf16* wvb = (bf16*)(base + 12582912);   //  2 MB
  bf16* Qb  = (bf16*)(base + 14680064);   //  8 MB
  bf16* Kb  = (bf16*)(base + 23068672);   //  8 MB
  bf16* Vtb = (bf16*)(base + 31457280);   //  8 MB  [1024x4096] transposed
  float* Sc = (float*)(base + 39845888);  // 64 MB  [4096x4096] fp32
  bf16* P   = (bf16*)(base + 106954752);  // 32 MB  [4096x4096] bf16
  // total ws use: 140,509,184 bytes

  cast_kernel<<<4096, 256, 0, stream>>>(x, xb, SEQ * DIN);
  cast_kernel<<<1024, 256, 0, stream>>>(Wq, wqb, DOUT * DIN);
  cast_kernel<<<1024, 256, 0, stream>>>(Wk, wkb, DOUT * DIN);
  cast_kernel<<<1024, 256, 0, stream>>>(Wv, wvb, DOUT * DIN);

  qkv_kernel<<<dim3(DOUT / 128, SEQ / 128, 3), 256, 0, stream>>>(xb, wqb, wkb, wvb, Qb, Kb, Vtb);
  scores_kernel<<<dim3(SEQ / 128, SEQ / 128), 256, 0, stream>>>(Qb, Kb, Sc);
  softmax_kernel<<<SEQ, 256, 0, stream>>>(Sc, P);
  pv_kernel<<<dim3(DOUT / 128, SEQ / 128), 256, 0, stream>>>(P, Vtb, Out);
}

// Round 2
// 183.275 us; speedup vs baseline: 1.1555x; 1.1555x over previous
//
#include <hip/hip_runtime.h>
#include <hip/hip_bf16.h>
#include <stdint.h>

#define SEQ 4096
#define DIN 1024
#define DOUT 1024

typedef __bf16 bf16;
typedef __bf16 bf16x4v __attribute__((ext_vector_type(4)));
typedef __bf16 bf16x8v __attribute__((ext_vector_type(8)));
typedef float f32x4 __attribute__((ext_vector_type(4)));

#define AS1 __attribute__((address_space(1)))
#define AS3 __attribute__((address_space(3)))

__device__ __forceinline__ void load_lds16(const void* g, void* l) {
  __builtin_amdgcn_global_load_lds((const AS1 uint32_t*)g, (AS3 uint32_t*)l, 16, 0, 0);
}

// ---------------- cast fp32 -> bf16, 4 elems/thread ----------------
__global__ __launch_bounds__(256) void cast_kernel(const float* __restrict__ in,
                                                   bf16* __restrict__ out, int n) {
  int i = (blockIdx.x * 256 + threadIdx.x) * 4;
  if (i >= n) return;
  float4 v = *reinterpret_cast<const float4*>(in + i);
  bf16x4v o;
  o[0] = (bf16)v.x; o[1] = (bf16)v.y; o[2] = (bf16)v.z; o[3] = (bf16)v.w;
  *reinterpret_cast<bf16x4v*>(out + i) = o;
}

// ---------------- BT GEMM core: C[128x128] += A[brow..][k] * B[bcol..][k]^T ----
// A: [M x lda] bf16 row-major, B: [N x ldb] bf16 row-major (K contiguous both).
// 256 threads = 4 waves (2x2), each wave 64x64 out = 4x4 frags of 16x16x32 MFMA.
__device__ __forceinline__ void gemm_bt_core(const bf16* __restrict__ A,
                                             const bf16* __restrict__ B,
                                             int lda, int ldb, int brow, int bcol,
                                             int kbeg, int kend, f32x4 acc[4][4],
                                             bf16* At, bf16* Bt) {
  const int tid = threadIdx.x;
  const int lane = tid & 63;

  // staging: linear LDS offsets, 2 issues per operand (256 thr * 16B = 4KB each)
  const int off0 = tid * 16;        // [0, 4096)
  const int off1 = off0 + 4096;     // [4096, 8192)
  const int r0 = off0 >> 6, c0 = off0 & 63;   // tile row / byte-in-row (64B rows)
  const int r1 = off1 >> 6, c1 = off1 & 63;
  const char* A0 = (const char*)A + (size_t)(brow + r0) * (size_t)(lda * 2) + c0;
  const char* A1 = (const char*)A + (size_t)(brow + r1) * (size_t)(lda * 2) + c1;
  const char* B0 = (const char*)B + (size_t)(bcol + r0) * (size_t)(ldb * 2) + c0;
  const char* B1 = (const char*)B + (size_t)(bcol + r1) * (size_t)(ldb * 2) + c1;

  const int wr = (tid >> 7) & 1;
  const int wc = (tid >> 6) & 1;
  const int lrow = lane & 15;
  const int lk = (lane >> 4) * 16;  // byte offset of this lane's k-group

  for (int k0 = kbeg; k0 < kend; k0 += 32) {
    const size_t kb = (size_t)k0 * 2;
    load_lds16(A0 + kb, (char*)At + off0);
    load_lds16(A1 + kb, (char*)At + off1);
    load_lds16(B0 + kb, (char*)Bt + off0);
    load_lds16(B1 + kb, (char*)Bt + off1);
    __syncthreads();   // includes vmcnt(0) drain

    bf16x8v a[4], b[4];
#pragma unroll
    for (int mt = 0; mt < 4; ++mt)
      a[mt] = *(const bf16x8v*)((const char*)At + ((wr * 64 + mt * 16 + lrow) * 64 + lk));
#pragma unroll
    for (int nt = 0; nt < 4; ++nt)
      b[nt] = *(const bf16x8v*)((const char*)Bt + ((wc * 64 + nt * 16 + lrow) * 64 + lk));
#pragma unroll
    for (int mt = 0; mt < 4; ++mt)
#pragma unroll
      for (int nt = 0; nt < 4; ++nt)
        acc[mt][nt] = __builtin_amdgcn_mfma_f32_16x16x32_bf16(a[mt], b[nt], acc[mt][nt], 0, 0, 0);
    __syncthreads();
  }
}

#define ACC_INIT()                    \
  f32x4 acc[4][4];                    \
  {                                   \
    f32x4 z = {0.f, 0.f, 0.f, 0.f};  \
    for (int m = 0; m < 4; ++m)       \
      for (int n = 0; n < 4; ++n) acc[m][n] = z; \
  }

// ---------------- QKV projection: Q,K row-major bf16; V written transposed ----
__global__ __launch_bounds__(256) void qkv_kernel(const bf16* __restrict__ xb,
                                                  const bf16* __restrict__ Wq,
                                                  const bf16* __restrict__ Wk,
                                                  const bf16* __restrict__ Wv,
                                                  bf16* __restrict__ Q,
                                                  bf16* __restrict__ K,
                                                  bf16* __restrict__ Vt) {
  __shared__ bf16 At[128 * 32];
  __shared__ bf16 Bt[128 * 32];
  const int bj = blockIdx.x, bi = blockIdx.y, z = blockIdx.z;
  const bf16* W = (z == 0) ? Wq : (z == 1) ? Wk : Wv;
  ACC_INIT();
  gemm_bt_core(xb, W, DIN, DIN, bi * 128, bj * 128, 0, DIN, acc, At, Bt);
  const int lane = threadIdx.x & 63;
  const int wr = (threadIdx.x >> 7) & 1, wc = (threadIdx.x >> 6) & 1;
  const int rbase = bi * 128 + wr * 64 + ((lane >> 4) << 2);
  const int cbase = bj * 128 + wc * 64 + (lane & 15);
  if (z < 2) {
    bf16* O = (z == 0) ? Q : K;
#pragma unroll
    for (int mt = 0; mt < 4; ++mt)
#pragma unroll
      for (int nt = 0; nt < 4; ++nt)
#pragma unroll
        for (int j = 0; j < 4; ++j)
          O[(size_t)(rbase + mt * 16 + j) * DOUT + (cbase + nt * 16)] = (bf16)acc[mt][nt][j];
  } else {
#pragma unroll
    for (int mt = 0; mt < 4; ++mt)
#pragma unroll
      for (int nt = 0; nt < 4; ++nt)
#pragma unroll
        for (int j = 0; j < 4; ++j)
          Vt[(size_t)(cbase + nt * 16) * SEQ + (rbase + mt * 16 + j)] = (bf16)acc[mt][nt][j];
  }
}

// ---------------- scores = Q @ K^T * scale, exact lower-triangle grid ---------
__global__ __launch_bounds__(256) void scores_kernel(const bf16* __restrict__ Q,
                                                     const bf16* __restrict__ Km,
                                                     float* __restrict__ Sc) {
  const int t = blockIdx.x;  // 0..527 triangular index
  int bi = (int)((sqrtf(8.0f * (float)t + 1.0f) - 1.0f) * 0.5f);
  while ((bi + 1) * (bi + 2) / 2 <= t) ++bi;
  while (bi * (bi + 1) / 2 > t) --bi;
  const int bj = t - bi * (bi + 1) / 2;
  __shared__ bf16 At[128 * 32];
  __shared__ bf16 Bt[128 * 32];
  ACC_INIT();
  gemm_bt_core(Q, Km, DOUT, DOUT, bi * 128, bj * 128, 0, DOUT, acc, At, Bt);
  const int lane = threadIdx.x & 63;
  const int wr = (threadIdx.x >> 7) & 1, wc = (threadIdx.x >> 6) & 1;
  const int rbase = bi * 128 + wr * 64 + ((lane >> 4) << 2);
  const int cbase = bj * 128 + wc * 64 + (lane & 15);
  const float scale = 0.03125f;  // 1/sqrt(1024)
#pragma unroll
  for (int mt = 0; mt < 4; ++mt)
#pragma unroll
    for (int nt = 0; nt < 4; ++nt)
#pragma unroll
      for (int j = 0; j < 4; ++j)
        Sc[(size_t)(rbase + mt * 16 + j) * SEQ + (cbase + nt * 16)] = acc[mt][nt][j] * scale;
}

// ---------------- row softmax (vectorized): P[r][0..r]=softmax, zero-pad ------
__global__ __launch_bounds__(256) void softmax_kernel(const float* __restrict__ Sc,
                                                      bf16* __restrict__ P) {
  __shared__ float rowbuf[SEQ];
  __shared__ float red[8];
  const int r = blockIdx.x;
  const int n = r + 1;
  const int nw4 = ((r >> 7) + 1) << 5;  // padded row length / 4
  const int tid = threadIdx.x;
  const float* src = Sc + (size_t)r * SEQ;
  const float NEG = -__builtin_inff();

  float lmax = NEG;
  for (int g = tid; g < nw4; g += 256) {
    float4 v = reinterpret_cast<const float4*>(src)[g];
    const int b = g * 4;
    v.x = (b + 0 < n) ? v.x : NEG;
    v.y = (b + 1 < n) ? v.y : NEG;
    v.z = (b + 2 < n) ? v.z : NEG;
    v.w = (b + 3 < n) ? v.w : NEG;
    reinterpret_cast<float4*>(rowbuf)[g] = v;
    lmax = fmaxf(fmaxf(lmax, fmaxf(v.x, v.y)), fmaxf(v.z, v.w));
  }
#pragma unroll
  for (int m = 32; m >= 1; m >>= 1) lmax = fmaxf(lmax, __shfl_xor(lmax, m, 64));
  if ((tid & 63) == 0) red[tid >> 6] = lmax;
  __syncthreads();
  const float rmax = fmaxf(fmaxf(red[0], red[1]), fmaxf(red[2], red[3]));

  float lsum = 0.f;
  for (int g = tid; g < nw4; g += 256) {
    float4 v = reinterpret_cast<const float4*>(rowbuf)[g];
    v.x = __expf(v.x - rmax);
    v.y = __expf(v.y - rmax);
    v.z = __expf(v.z - rmax);
    v.w = __expf(v.w - rmax);
    reinterpret_cast<float4*>(rowbuf)[g] = v;
    lsum += v.x + v.y + v.z + v.w;
  }
#pragma unroll
  for (int m = 32; m >= 1; m >>= 1) lsum += __shfl_xor(lsum, m, 64);
  if ((tid & 63) == 0) red[4 + (tid >> 6)] = lsum;
  __syncthreads();
  const float inv = 1.0f / (red[4] + red[5] + red[6] + red[7]);

  bf16* dst = P + (size_t)r * SEQ;
  for (int g = tid; g < nw4; g += 256) {
    float4 v = reinterpret_cast<const float4*>(rowbuf)[g];
    bf16x4v o;
    o[0] = (bf16)(v.x * inv);
    o[1] = (bf16)(v.y * inv);
    o[2] = (bf16)(v.z * inv);
    o[3] = (bf16)(v.w * inv);
    *reinterpret_cast<bf16x4v*>(dst + g * 4) = o;
  }
}

// ---------------- out += P @ V (split-K, balanced, atomic accumulate) ---------
// blockIdx.x = bj (d-out col block), blockIdx.y = linear K-chunk over all bi.
// Chunk = 512 K-elems (16 BK-iters). chunks(bi) = ceil((bi+1)*128/512).
__global__ __launch_bounds__(256) void pv_kernel(const bf16* __restrict__ P,
                                                 const bf16* __restrict__ Vt,
                                                 float* __restrict__ Out) {
  __shared__ bf16 At[128 * 32];
  __shared__ bf16 Bt[128 * 32];
  const int bj = blockIdx.x;
  int c = blockIdx.y, bi = 0;
  for (;;) {
    const int nch = (bi + 4) >> 2;  // ceil((bi+1)/4)
    if (c < nch) break;
    c -= nch; ++bi;
  }
  const int k0 = c * 512;
  const int kend = min((bi + 1) * 128, k0 + 512);
  ACC_INIT();
  gemm_bt_core(P, Vt, SEQ, SEQ, bi * 128, bj * 128, k0, kend, acc, At, Bt);
  const int lane = threadIdx.x & 63;
  const int wr = (threadIdx.x >> 7) & 1, wc = (threadIdx.x >> 6) & 1;
  const int rbase = bi * 128 + wr * 64 + ((lane >> 4) << 2);
  const int cbase = bj * 128 + wc * 64 + (lane & 15);
#pragma unroll
  for (int mt = 0; mt < 4; ++mt)
#pragma unroll
    for (int nt = 0; nt < 4; ++nt)
#pragma unroll
      for (int j = 0; j < 4; ++j)
        atomicAdd(&Out[(size_t)(rbase + mt * 16 + j) * DOUT + (cbase + nt * 16)],
                  acc[mt][nt][j]);
}

extern "C" void kernel_launch(void* const* d_in, const int* in_sizes, int n_in,
                              void* d_out, int out_size, void* d_ws, size_t ws_size,
                              hipStream_t stream) {
  const float* x  = (const float*)d_in[0];
  const float* Wq = (const float*)d_in[1];
  const float* Wk = (const float*)d_in[2];
  const float* Wv = (const float*)d_in[3];
  float* Out = (float*)d_out;

  char* base = (char*)d_ws;
  bf16* xb  = (bf16*)(base + 0);          //  8 MB  [4096x1024]
  bf16* wqb = (bf16*)(base + 8388608);    //  2 MB
  bf16* wkb = (bf16*)(base + 10485760);   //  2 MB
  bf16* wvb = (bf16*)(base + 12582912);   //  2 MB
  bf16* Qb  = (bf16*)(base + 14680064);   //  8 MB
  bf16* Kb  = (bf16*)(base + 23068672);   //  8 MB
  bf16* Vtb = (bf16*)(base + 31457280);   //  8 MB  [1024x4096] transposed
  float* Sc = (float*)(base + 39845888);  // 64 MB  [4096x4096] fp32
  bf16* P   = (bf16*)(base + 106954752);  // 32 MB  [4096x4096] bf16
  // total ws use: 140,509,184 bytes

  hipMemsetAsync(d_out, 0, (size_t)out_size * sizeof(float), stream);

  cast_kernel<<<4096, 256, 0, stream>>>(x, xb, SEQ * DIN);
  cast_kernel<<<1024, 256, 0, stream>>>(Wq, wqb, DOUT * DIN);
  cast_kernel<<<1024, 256, 0, stream>>>(Wk, wkb, DOUT * DIN);
  cast_kernel<<<1024, 256, 0, stream>>>(Wv, wvb, DOUT * DIN);

  qkv_kernel<<<dim3(DOUT / 128, SEQ / 128, 3), 256, 0, stream>>>(xb, wqb, wkb, wvb, Qb, Kb, Vtb);
  scores_kernel<<<528, 256, 0, stream>>>(Qb, Kb, Sc);
  softmax_kernel<<<SEQ, 256, 0, stream>>>(Sc, P);
  pv_kernel<<<dim3(DOUT / 128, 144), 256, 0, stream>>>(P, Vtb, Out);
}

// Round 3
// 166.622 us; speedup vs baseline: 1.2709x; 1.0999x over previous
//
#include <hip/hip_runtime.h>
#include <hip/hip_bf16.h>
#include <stdint.h>

#define SEQ 4096
#define DIN 1024
#define DOUT 1024

typedef __bf16 bf16;
typedef __bf16 bf16x4v __attribute__((ext_vector_type(4)));
typedef __bf16 bf16x8v __attribute__((ext_vector_type(8)));
typedef float f32x4 __attribute__((ext_vector_type(4)));

#define AS1 __attribute__((address_space(1)))
#define AS3 __attribute__((address_space(3)))

__device__ __forceinline__ void load_lds16(const void* g, void* l) {
  __builtin_amdgcn_global_load_lds((const AS1 uint32_t*)g, (AS3 uint32_t*)l, 16, 0, 0);
}

__device__ __forceinline__ int imin(int a, int b) { return a < b ? a : b; }

// ---------------- fused cast fp32 -> bf16 for x, Wq, Wk, Wv -------------------
__global__ __launch_bounds__(256) void cast_all_kernel(
    const float* __restrict__ x, const float* __restrict__ wq,
    const float* __restrict__ wk, const float* __restrict__ wv,
    bf16* __restrict__ xb, bf16* __restrict__ wqb,
    bf16* __restrict__ wkb, bf16* __restrict__ wvb) {
  const int y = blockIdx.y;
  const float* in = (y == 0) ? x : (y == 1) ? wq : (y == 2) ? wk : wv;
  bf16* out = (y == 0) ? xb : (y == 1) ? wqb : (y == 2) ? wkb : wvb;
  const int n = (y == 0) ? SEQ * DIN : DOUT * DIN;
  int i = (blockIdx.x * 256 + threadIdx.x) * 4;
  if (i >= n) return;
  float4 v = *reinterpret_cast<const float4*>(in + i);
  bf16x4v o;
  o[0] = (bf16)v.x; o[1] = (bf16)v.y; o[2] = (bf16)v.z; o[3] = (bf16)v.w;
  *reinterpret_cast<bf16x4v*>(out + i) = o;
}

// ---------------- BT GEMM core, 2-phase double-buffered ----------------------
// C[128x128] += A[brow..][k] * B[bcol..][k]^T over k in [kbeg,kend).
// A: [M x lda] bf16 row-major, B: [N x ldb] bf16 row-major (K contiguous both).
// 256 threads = 4 waves (2x2), each wave 64x64 out = 4x4 frags of 16x16x32 MFMA.
// At/Bt: 2 buffers of 128x32 bf16 each (8 KB per buffer, 16 KB per operand).
__device__ __forceinline__ void gemm_bt_core(const bf16* __restrict__ A,
                                             const bf16* __restrict__ B,
                                             int lda, int ldb, int brow, int bcol,
                                             int kbeg, int kend, f32x4 acc[4][4],
                                             bf16* At, bf16* Bt) {
  const int tid = threadIdx.x;
  const int lane = tid & 63;

  // staging: linear LDS offsets, 2 issues per operand (256 thr * 16B = 4KB each)
  const int off0 = tid * 16;        // [0, 4096)
  const int off1 = off0 + 4096;     // [4096, 8192)
  const int r0 = off0 >> 6, c0 = off0 & 63;   // tile row / byte-in-row (64B rows)
  const int r1 = off1 >> 6, c1 = off1 & 63;
  const char* A0 = (const char*)A + (size_t)(brow + r0) * (size_t)(lda * 2) + c0;
  const char* A1 = (const char*)A + (size_t)(brow + r1) * (size_t)(lda * 2) + c1;
  const char* B0 = (const char*)B + (size_t)(bcol + r0) * (size_t)(ldb * 2) + c0;
  const char* B1 = (const char*)B + (size_t)(bcol + r1) * (size_t)(ldb * 2) + c1;

  const int wr = (tid >> 7) & 1;
  const int wc = (tid >> 6) & 1;
  const int lrow = lane & 15;
  const int lk = (lane >> 4) * 16;  // byte offset of this lane's k-group

  char* AtB = (char*)At;
  char* BtB = (char*)Bt;

#define STAGE(buf, kk) do {                                   \
    const size_t kb_ = (size_t)(kk) * 2;                      \
    load_lds16(A0 + kb_, AtB + (buf) * 8192 + off0);          \
    load_lds16(A1 + kb_, AtB + (buf) * 8192 + off1);          \
    load_lds16(B0 + kb_, BtB + (buf) * 8192 + off0);          \
    load_lds16(B1 + kb_, BtB + (buf) * 8192 + off1);          \
  } while (0)

  // prologue: stage first tile, drain, barrier
  STAGE(0, kbeg);
  asm volatile("s_waitcnt vmcnt(0)" ::: "memory");
  __builtin_amdgcn_s_barrier();

  int cur = 0;
  for (int k0 = kbeg; k0 < kend; k0 += 32) {
    const int nxt = k0 + 32;
    if (nxt < kend) STAGE(cur ^ 1, nxt);  // issue next-tile loads; they fly under compute

    const char* Ab = AtB + cur * 8192;
    const char* Bb = BtB + cur * 8192;
    bf16x8v a[4], b[4];
#pragma unroll
    for (int mt = 0; mt < 4; ++mt)
      a[mt] = *(const bf16x8v*)(Ab + ((wr * 64 + mt * 16 + lrow) * 64 + lk));
#pragma unroll
    for (int nt = 0; nt < 4; ++nt)
      b[nt] = *(const bf16x8v*)(Bb + ((wc * 64 + nt * 16 + lrow) * 64 + lk));
#pragma unroll
    for (int mt = 0; mt < 4; ++mt)
#pragma unroll
      for (int nt = 0; nt < 4; ++nt)
        acc[mt][nt] = __builtin_amdgcn_mfma_f32_16x16x32_bf16(a[mt], b[nt], acc[mt][nt], 0, 0, 0);

    asm volatile("s_waitcnt vmcnt(0)" ::: "memory");  // next tile landed
    __builtin_amdgcn_s_barrier();                     // all waves done with cur
    cur ^= 1;
  }
#undef STAGE
}

#define ACC_INIT()                    \
  f32x4 acc[4][4];                    \
  {                                   \
    f32x4 z = {0.f, 0.f, 0.f, 0.f};  \
    for (int m = 0; m < 4; ++m)       \
      for (int n = 0; n < 4; ++n) acc[m][n] = z; \
  }

// ---------------- QKV projection: Q,K row-major bf16; V written transposed ----
__global__ __launch_bounds__(256) void qkv_kernel(const bf16* __restrict__ xb,
                                                  const bf16* __restrict__ Wq,
                                                  const bf16* __restrict__ Wk,
                                                  const bf16* __restrict__ Wv,
                                                  bf16* __restrict__ Q,
                                                  bf16* __restrict__ K,
                                                  bf16* __restrict__ Vt) {
  __shared__ bf16 At[2 * 128 * 32];
  __shared__ bf16 Bt[2 * 128 * 32];
  const int bj = blockIdx.x, bi = blockIdx.y, z = blockIdx.z;
  const bf16* W = (z == 0) ? Wq : (z == 1) ? Wk : Wv;
  ACC_INIT();
  gemm_bt_core(xb, W, DIN, DIN, bi * 128, bj * 128, 0, DIN, acc, At, Bt);
  const int lane = threadIdx.x & 63;
  const int wr = (threadIdx.x >> 7) & 1, wc = (threadIdx.x >> 6) & 1;
  const int rbase = bi * 128 + wr * 64 + ((lane >> 4) << 2);
  const int cbase = bj * 128 + wc * 64 + (lane & 15);
  if (z < 2) {
    bf16* O = (z == 0) ? Q : K;
#pragma unroll
    for (int mt = 0; mt < 4; ++mt)
#pragma unroll
      for (int nt = 0; nt < 4; ++nt)
#pragma unroll
        for (int j = 0; j < 4; ++j)
          O[(size_t)(rbase + mt * 16 + j) * DOUT + (cbase + nt * 16)] = (bf16)acc[mt][nt][j];
  } else {
#pragma unroll
    for (int mt = 0; mt < 4; ++mt)
#pragma unroll
      for (int nt = 0; nt < 4; ++nt)
#pragma unroll
        for (int j = 0; j < 4; ++j)
          Vt[(size_t)(cbase + nt * 16) * SEQ + (rbase + mt * 16 + j)] = (bf16)acc[mt][nt][j];
  }
}

// ---------------- scores = Q @ K^T * scale, exact lower-triangle grid ---------
__global__ __launch_bounds__(256) void scores_kernel(const bf16* __restrict__ Q,
                                                     const bf16* __restrict__ Km,
                                                     float* __restrict__ Sc) {
  const int t = blockIdx.x;  // 0..527 triangular index
  int bi = (int)((sqrtf(8.0f * (float)t + 1.0f) - 1.0f) * 0.5f);
  while ((bi + 1) * (bi + 2) / 2 <= t) ++bi;
  while (bi * (bi + 1) / 2 > t) --bi;
  const int bj = t - bi * (bi + 1) / 2;
  __shared__ bf16 At[2 * 128 * 32];
  __shared__ bf16 Bt[2 * 128 * 32];
  ACC_INIT();
  gemm_bt_core(Q, Km, DOUT, DOUT, bi * 128, bj * 128, 0, DOUT, acc, At, Bt);
  const int lane = threadIdx.x & 63;
  const int wr = (threadIdx.x >> 7) & 1, wc = (threadIdx.x >> 6) & 1;
  const int rbase = bi * 128 + wr * 64 + ((lane >> 4) << 2);
  const int cbase = bj * 128 + wc * 64 + (lane & 15);
  const float scale = 0.03125f;  // 1/sqrt(1024)
#pragma unroll
  for (int mt = 0; mt < 4; ++mt)
#pragma unroll
    for (int nt = 0; nt < 4; ++nt)
#pragma unroll
      for (int j = 0; j < 4; ++j)
        Sc[(size_t)(rbase + mt * 16 + j) * SEQ + (cbase + nt * 16)] = acc[mt][nt][j] * scale;
}

// ---------------- row softmax (vectorized): P[r][0..r]=softmax, zero-pad ------
__global__ __launch_bounds__(256) void softmax_kernel(const float* __restrict__ Sc,
                                                      bf16* __restrict__ P) {
  __shared__ float rowbuf[SEQ];
  __shared__ float red[8];
  const int r = blockIdx.x;
  const int n = r + 1;
  const int nw4 = ((r >> 7) + 1) << 5;  // padded row length / 4
  const int tid = threadIdx.x;
  const float* src = Sc + (size_t)r * SEQ;
  const float NEG = -__builtin_inff();

  float lmax = NEG;
  for (int g = tid; g < nw4; g += 256) {
    float4 v = reinterpret_cast<const float4*>(src)[g];
    const int b = g * 4;
    v.x = (b + 0 < n) ? v.x : NEG;
    v.y = (b + 1 < n) ? v.y : NEG;
    v.z = (b + 2 < n) ? v.z : NEG;
    v.w = (b + 3 < n) ? v.w : NEG;
    reinterpret_cast<float4*>(rowbuf)[g] = v;
    lmax = fmaxf(fmaxf(lmax, fmaxf(v.x, v.y)), fmaxf(v.z, v.w));
  }
#pragma unroll
  for (int m = 32; m >= 1; m >>= 1) lmax = fmaxf(lmax, __shfl_xor(lmax, m, 64));
  if ((tid & 63) == 0) red[tid >> 6] = lmax;
  __syncthreads();
  const float rmax = fmaxf(fmaxf(red[0], red[1]), fmaxf(red[2], red[3]));

  float lsum = 0.f;
  for (int g = tid; g < nw4; g += 256) {
    float4 v = reinterpret_cast<const float4*>(rowbuf)[g];
    v.x = __expf(v.x - rmax);
    v.y = __expf(v.y - rmax);
    v.z = __expf(v.z - rmax);
    v.w = __expf(v.w - rmax);
    reinterpret_cast<float4*>(rowbuf)[g] = v;
    lsum += v.x + v.y + v.z + v.w;
  }
#pragma unroll
  for (int m = 32; m >= 1; m >>= 1) lsum += __shfl_xor(lsum, m, 64);
  if ((tid & 63) == 0) red[4 + (tid >> 6)] = lsum;
  __syncthreads();
  const float inv = 1.0f / (red[4] + red[5] + red[6] + red[7]);

  bf16* dst = P + (size_t)r * SEQ;
  for (int g = tid; g < nw4; g += 256) {
    float4 v = reinterpret_cast<const float4*>(rowbuf)[g];
    bf16x4v o;
    o[0] = (bf16)(v.x * inv);
    o[1] = (bf16)(v.y * inv);
    o[2] = (bf16)(v.z * inv);
    o[3] = (bf16)(v.w * inv);
    *reinterpret_cast<bf16x4v*>(dst + g * 4) = o;
  }
}

// ---------------- out += P @ V (balanced split-K, atomic accumulate) ----------
// blockIdx.x = bj (d-out col block), blockIdx.y = linear chunk over all bi.
// Per block-row bi: Ti=(bi+1)*4 BK-iters split into nch=ceil((bi+1)/8) chunks
// of <=32 iters, balanced. bi<8 has a single writer -> plain store.
__global__ __launch_bounds__(256) void pv_kernel(const bf16* __restrict__ P,
                                                 const bf16* __restrict__ Vt,
                                                 float* __restrict__ Out) {
  __shared__ bf16 At[2 * 128 * 32];
  __shared__ bf16 Bt[2 * 128 * 32];
  const int bj = blockIdx.x;
  int c = blockIdx.y, bi = 0;
  for (;;) {
    const int nch = (bi + 8) >> 3;  // ceil((bi+1)/8)
    if (c < nch) break;
    c -= nch; ++bi;
  }
  const int nch = (bi + 8) >> 3;
  const int Ti = (bi + 1) * 4;
  const int base = Ti / nch, rem = Ti % nch;
  const int it0 = c * base + imin(c, rem);
  const int itn = base + (c < rem ? 1 : 0);
  const int k0 = it0 * 32;
  const int kend = k0 + itn * 32;
  ACC_INIT();
  gemm_bt_core(P, Vt, SEQ, SEQ, bi * 128, bj * 128, k0, kend, acc, At, Bt);
  const int lane = threadIdx.x & 63;
  const int wr = (threadIdx.x >> 7) & 1, wc = (threadIdx.x >> 6) & 1;
  const int rbase = bi * 128 + wr * 64 + ((lane >> 4) << 2);
  const int cbase = bj * 128 + wc * 64 + (lane & 15);
  if (nch == 1) {
#pragma unroll
    for (int mt = 0; mt < 4; ++mt)
#pragma unroll
      for (int nt = 0; nt < 4; ++nt)
#pragma unroll
        for (int j = 0; j < 4; ++j)
          Out[(size_t)(rbase + mt * 16 + j) * DOUT + (cbase + nt * 16)] = acc[mt][nt][j];
  } else {
#pragma unroll
    for (int mt = 0; mt < 4; ++mt)
#pragma unroll
      for (int nt = 0; nt < 4; ++nt)
#pragma unroll
        for (int j = 0; j < 4; ++j)
          atomicAdd(&Out[(size_t)(rbase + mt * 16 + j) * DOUT + (cbase + nt * 16)],
                    acc[mt][nt][j]);
  }
}

extern "C" void kernel_launch(void* const* d_in, const int* in_sizes, int n_in,
                              void* d_out, int out_size, void* d_ws, size_t ws_size,
                              hipStream_t stream) {
  const float* x  = (const float*)d_in[0];
  const float* Wq = (const float*)d_in[1];
  const float* Wk = (const float*)d_in[2];
  const float* Wv = (const float*)d_in[3];
  float* Out = (float*)d_out;

  char* base = (char*)d_ws;
  bf16* xb  = (bf16*)(base + 0);          //  8 MB  [4096x1024]
  bf16* wqb = (bf16*)(base + 8388608);    //  2 MB
  bf16* wkb = (bf16*)(base + 10485760);   //  2 MB
  bf16* wvb = (bf16*)(base + 12582912);   //  2 MB
  bf16* Qb  = (bf16*)(base + 14680064);   //  8 MB
  bf16* Kb  = (bf16*)(base + 23068672);   //  8 MB
  bf16* Vtb = (bf16*)(base + 31457280);   //  8 MB  [1024x4096] transposed
  float* Sc = (float*)(base + 39845888);  // 64 MB  [4096x4096] fp32
  bf16* P   = (bf16*)(base + 106954752);  // 32 MB  [4096x4096] bf16
  // total ws use: 140,509,184 bytes

  hipMemsetAsync(d_out, 0, (size_t)out_size * sizeof(float), stream);

  cast_all_kernel<<<dim3(4096, 4), 256, 0, stream>>>(x, Wq, Wk, Wv, xb, wqb, wkb, wvb);

  qkv_kernel<<<dim3(DOUT / 128, SEQ / 128, 3), 256, 0, stream>>>(xb, wqb, wkb, wvb, Qb, Kb, Vtb);
  scores_kernel<<<528, 256, 0, stream>>>(Qb, Kb, Sc);
  softmax_kernel<<<SEQ, 256, 0, stream>>>(Sc, P);
  pv_kernel<<<dim3(DOUT / 128, 80), 256, 0, stream>>>(P, Vtb, Out);
}